// Round 6
// baseline (27.698 us; speedup 1.0000x reference)
//
#include <hip/hip_runtime.h>
#include <float.h>

// Chamfer distance, B=16, N=2048, D=3, fp32.
// cd[b] = mean_j min_i |x_i - y_j|^2 + mean_i min_j |x_i - y_j|^2
// Pair form: |q - r|^2 = 2*(0.5|r|^2 - q.r) + |q|^2.
// v2f lanes = two consecutive REF points (natural ds_read_b64 of SoA LDS
// rows); query splats {-q,-q} are loop-invariant registers. Inner loop is
// pure v_pk_fma_f32 + v_min3_f32 with zero splat movs. QPT=4 + 2048 blocks
// -> 8 waves/SIMD for latency hiding.

constexpr int B_ = 16;
constexpr int N_ = 2048;
constexpr int THREADS = 256;
constexpr int QPT = 4;                  // queries per thread
constexpr int QBLK = THREADS * QPT;     // 1024 queries per block
constexpr int QSLICES = N_ / QBLK;      // 2 query slices
constexpr int SLICES = N_ / THREADS;    // 8 combine slices per (dir,b)

typedef float v2f __attribute__((ext_vector_type(2)));

// ws layout: float partial[2][B_][NJC][N_], then float sums[2][B_][SLICES]

template <int NJC>
__global__ __launch_bounds__(THREADS, 8)
void cd_min_kernel(const float* __restrict__ x,
                   const float* __restrict__ y,
                   float* __restrict__ partial) {
    constexpr int CHUNK = N_ / NJC;     // 64 for NJC=32
    const int jc  = (int)blockIdx.x % NJC;
    const int qs  = (int)blockIdx.x / NJC;
    const int b   = blockIdx.y;
    const int dir = blockIdx.z;

    const float* __restrict__ q = dir ? y : x;
    const float* __restrict__ r = dir ? x : y;

    // ---- stage ref chunk into LDS, SoA + half-norm row ----
    __shared__ float lref[4][CHUNK];    // [x|y|z|0.5*|r|^2][point]
    {
        const float* __restrict__ rp =
            r + ((size_t)b * N_ + (size_t)jc * CHUNK) * 3;
        for (int p = (int)threadIdx.x; p < CHUNK; p += THREADS) {
            const float rx = rp[3 * p + 0];
            const float ry = rp[3 * p + 1];
            const float rz = rp[3 * p + 2];
            lref[0][p] = rx;
            lref[1][p] = ry;
            lref[2][p] = rz;
            lref[3][p] = 0.5f * (rx * rx + ry * ry + rz * rz);
        }
    }

    // ---- per-thread query registers: loop-invariant splats ----
    const int i0 = qs * QBLK + (int)threadIdx.x * QPT;
    const float* qp = q + ((size_t)b * N_ + i0) * 3;

    v2f QX[QPT], QY[QPT], QZ[QPT], best[QPT];
    float q2[QPT];
    #pragma unroll
    for (int k = 0; k < QPT; ++k) {
        const float a0 = qp[3 * k + 0];
        const float a1 = qp[3 * k + 1];
        const float a2 = qp[3 * k + 2];
        QX[k] = (v2f){-a0, -a0};
        QY[k] = (v2f){-a1, -a1};
        QZ[k] = (v2f){-a2, -a2};
        q2[k] = a0 * a0 + a1 * a1 + a2 * a2;
        best[k] = (v2f){FLT_MAX, FLT_MAX};
    }
    __syncthreads();

    // ---- main loop: 4 refs/iter, v2f = {ref_j, ref_j+1} straight from LDS.
    const v2f* __restrict__ lx = (const v2f*)lref[0];
    const v2f* __restrict__ ly = (const v2f*)lref[1];
    const v2f* __restrict__ lz = (const v2f*)lref[2];
    const v2f* __restrict__ lh = (const v2f*)lref[3];

    #pragma unroll 2
    for (int j4 = 0; j4 < CHUNK / 4; ++j4) {
        const v2f sx0 = lx[2 * j4], sx1 = lx[2 * j4 + 1];
        const v2f sy0 = ly[2 * j4], sy1 = ly[2 * j4 + 1];
        const v2f sz0 = lz[2 * j4], sz1 = lz[2 * j4 + 1];
        const v2f sh0 = lh[2 * j4], sh1 = lh[2 * j4 + 1];
        #pragma unroll
        for (int k = 0; k < QPT; ++k) {
            v2f a = __builtin_elementwise_fma(QX[k], sx0, sh0);
            a = __builtin_elementwise_fma(QY[k], sy0, a);
            a = __builtin_elementwise_fma(QZ[k], sz0, a);
            v2f c = __builtin_elementwise_fma(QX[k], sx1, sh1);
            c = __builtin_elementwise_fma(QY[k], sy1, c);
            c = __builtin_elementwise_fma(QZ[k], sz1, c);
            // per-component min3: min(best, min(a, c))
            best[k] = __builtin_elementwise_min(
                best[k], __builtin_elementwise_min(a, c));
        }
    }

    float res[QPT];
    #pragma unroll
    for (int k = 0; k < QPT; ++k)
        res[k] = 2.0f * fminf(best[k].x, best[k].y) + q2[k];

    float4* op = (float4*)(partial
        + (((size_t)dir * B_ + b) * NJC + jc) * N_ + i0);
    op[0] = *(float4*)&res[0];
}

// Stage 2: grid (B_, 2, SLICES). Min over NJC chunks (fully unrolled ->
// batched vmcnt loads), then block-sum -> sums[dir][b][slice].
template <int NJC>
__global__ __launch_bounds__(THREADS)
void cd_combine_kernel(const float* __restrict__ partial,
                       float* __restrict__ sums) {
    const int b     = blockIdx.x;
    const int dir   = blockIdx.y;
    const int slice = blockIdx.z;
    const int t     = (int)threadIdx.x;
    const int i     = slice * THREADS + t;

    const float* __restrict__ p =
        partial + ((size_t)dir * B_ + b) * (size_t)NJC * N_ + i;

    float m = FLT_MAX;
    #pragma unroll
    for (int c = 0; c < NJC; ++c)
        m = fminf(m, p[(size_t)c * N_]);

    float s = m;
    #pragma unroll
    for (int o = 32; o > 0; o >>= 1)
        s += __shfl_down(s, o, 64);

    __shared__ float red[THREADS / 64];
    if ((t & 63) == 0) red[t >> 6] = s;
    __syncthreads();
    if (t == 0) {
        float tot = 0.0f;
        #pragma unroll
        for (int w = 0; w < THREADS / 64; ++w) tot += red[w];
        sums[((size_t)dir * B_ + b) * SLICES + slice] = tot;
    }
}

// Stage 3: one block. Thread t -> b = t/16, k = t%16 -> (dir, slice).
__global__ __launch_bounds__(THREADS)
void cd_final_kernel(const float* __restrict__ sums,
                     float* __restrict__ out) {
    const int t   = (int)threadIdx.x;
    const int b   = t >> 4;
    const int k   = t & 15;
    const int dir = k >> 3;
    const int sl  = k & 7;

    float v = sums[((size_t)dir * B_ + b) * SLICES + sl];
    v += __shfl_down(v, 8, 16);
    v += __shfl_down(v, 4, 16);
    v += __shfl_down(v, 2, 16);
    v += __shfl_down(v, 1, 16);
    if (k == 0) out[b] = v * (1.0f / (float)N_);
}

extern "C" void kernel_launch(void* const* d_in, const int* in_sizes, int n_in,
                              void* d_out, int out_size, void* d_ws, size_t ws_size,
                              hipStream_t stream) {
    const float* x = (const float*)d_in[0];
    const float* y = (const float*)d_in[1];
    float* out     = (float*)d_out;
    float* partial = (float*)d_ws;

    auto need = [](int njc) -> size_t {
        return 2ull * B_ * njc * N_ * sizeof(float)
             + 2ull * B_ * SLICES * sizeof(float);
    };

    const dim3 gcomb(B_, 2, SLICES);
    if (ws_size >= need(32)) {
        float* sums = partial + 2ull * B_ * 32 * N_;
        cd_min_kernel<32><<<dim3(32 * QSLICES, B_, 2), dim3(THREADS), 0, stream>>>(x, y, partial);
        cd_combine_kernel<32><<<gcomb, dim3(THREADS), 0, stream>>>(partial, sums);
        cd_final_kernel<<<dim3(1), dim3(THREADS), 0, stream>>>(sums, out);
    } else if (ws_size >= need(16)) {
        float* sums = partial + 2ull * B_ * 16 * N_;
        cd_min_kernel<16><<<dim3(16 * QSLICES, B_, 2), dim3(THREADS), 0, stream>>>(x, y, partial);
        cd_combine_kernel<16><<<gcomb, dim3(THREADS), 0, stream>>>(partial, sums);
        cd_final_kernel<<<dim3(1), dim3(THREADS), 0, stream>>>(sums, out);
    } else {
        float* sums = partial + 2ull * B_ * 8 * N_;
        cd_min_kernel<8><<<dim3(8 * QSLICES, B_, 2), dim3(THREADS), 0, stream>>>(x, y, partial);
        cd_combine_kernel<8><<<gcomb, dim3(THREADS), 0, stream>>>(partial, sums);
        cd_final_kernel<<<dim3(1), dim3(THREADS), 0, stream>>>(sums, out);
    }
}

// Round 7
// 23.945 us; speedup vs baseline: 1.1567x; 1.1567x over previous
//
#include <hip/hip_runtime.h>
#include <float.h>

// Chamfer distance, B=16, N=2048, D=3, fp32.
// cd[b] = mean_j min_i |x_i - y_j|^2 + mean_i min_j |x_i - y_j|^2
// Pair form: |q - r|^2 = 2*(0.5|r|^2 - q.r) + |q|^2.
// KEY HW FACT: v_pk_fma_f32 is HALF-RATE on gfx950 (fp32 peak 157.3 TF ==
// scalar v_fma rate) -> scalar v_fma_f32 + v_min3_f32 is the optimal mix:
// 3 FMA + 0.5 min3 per pair = 3.5 instr/pair. Refs come 4-at-a-time from
// SoA LDS rows via ds_read_b128; scalar lane extraction is free.

constexpr int B_ = 16;
constexpr int N_ = 2048;
constexpr int THREADS = 256;
constexpr int QPT = 8;                  // queries per thread; THREADS*QPT == N_
constexpr int NJC = 32;                 // ref chunks
constexpr int CHUNK = N_ / NJC;         // 64 refs per chunk
constexpr int SLICES = N_ / THREADS;    // 8 combine slices per (dir,b)

typedef float v4f __attribute__((ext_vector_type(4)));

// ws layout: float partial[2][B_][NJC][N_], then float sums[2][B_][SLICES]

__global__ __launch_bounds__(THREADS)
void cd_min_kernel(const float* __restrict__ x,
                   const float* __restrict__ y,
                   float* __restrict__ partial) {
    const int jc  = blockIdx.x;
    const int b   = blockIdx.y;
    const int dir = blockIdx.z;

    const float* __restrict__ q = dir ? y : x;
    const float* __restrict__ r = dir ? x : y;

    // ---- stage ref chunk into LDS, SoA + half-norm row ----
    __shared__ float lref[4][CHUNK];    // [x|y|z|0.5*|r|^2][point]
    {
        const float* __restrict__ rp =
            r + ((size_t)b * N_ + (size_t)jc * CHUNK) * 3;
        for (int p = (int)threadIdx.x; p < CHUNK; p += THREADS) {
            const float rx = rp[3 * p + 0];
            const float ry = rp[3 * p + 1];
            const float rz = rp[3 * p + 2];
            lref[0][p] = rx;
            lref[1][p] = ry;
            lref[2][p] = rz;
            lref[3][p] = 0.5f * (rx * rx + ry * ry + rz * rz);
        }
    }

    // ---- per-thread query registers (negated; fma input-mod also free) ----
    const int i0 = (int)threadIdx.x * QPT;
    const float* qp = q + ((size_t)b * N_ + i0) * 3;

    // 8 queries * 3 floats = 96 B contiguous -> 6 float4 loads.
    float qf[24];
    {
        const float4* qv = (const float4*)qp;
        #pragma unroll
        for (int v = 0; v < 6; ++v) {
            const float4 t = qv[v];
            qf[4 * v + 0] = t.x; qf[4 * v + 1] = t.y;
            qf[4 * v + 2] = t.z; qf[4 * v + 3] = t.w;
        }
    }
    float qnx[QPT], qny[QPT], qnz[QPT], q2[QPT], best[QPT];
    #pragma unroll
    for (int k = 0; k < QPT; ++k) {
        const float a0 = qf[3 * k + 0];
        const float a1 = qf[3 * k + 1];
        const float a2 = qf[3 * k + 2];
        qnx[k] = -a0; qny[k] = -a1; qnz[k] = -a2;
        q2[k]  = a0 * a0 + a1 * a1 + a2 * a2;
        best[k] = FLT_MAX;
    }
    __syncthreads();

    // ---- main loop: 4 refs/group via 4x ds_read_b128 (broadcast) ----
    const v4f* __restrict__ lx = (const v4f*)lref[0];
    const v4f* __restrict__ ly = (const v4f*)lref[1];
    const v4f* __restrict__ lz = (const v4f*)lref[2];
    const v4f* __restrict__ lh = (const v4f*)lref[3];

    #pragma unroll 2
    for (int g = 0; g < CHUNK / 4; ++g) {
        const v4f X = lx[g], Y = ly[g], Z = lz[g], H = lh[g];
        #pragma unroll
        for (int k = 0; k < QPT; ++k) {
            float a0 = fmaf(qnx[k], X.x, H.x);
            a0 = fmaf(qny[k], Y.x, a0);
            a0 = fmaf(qnz[k], Z.x, a0);
            float a1 = fmaf(qnx[k], X.y, H.y);
            a1 = fmaf(qny[k], Y.y, a1);
            a1 = fmaf(qnz[k], Z.y, a1);
            float a2 = fmaf(qnx[k], X.z, H.z);
            a2 = fmaf(qny[k], Y.z, a2);
            a2 = fmaf(qnz[k], Z.z, a2);
            float a3 = fmaf(qnx[k], X.w, H.w);
            a3 = fmaf(qny[k], Y.w, a3);
            a3 = fmaf(qnz[k], Z.w, a3);
            // two v_min3_f32: min(best, a0, a1), min(best, a2, a3)
            best[k] = fminf(fminf(best[k], a0), a1);
            best[k] = fminf(fminf(best[k], a2), a3);
        }
    }

    float res[QPT];
    #pragma unroll
    for (int k = 0; k < QPT; ++k)
        res[k] = 2.0f * best[k] + q2[k];

    float4* op = (float4*)(partial
        + (((size_t)dir * B_ + b) * NJC + jc) * N_ + i0);
    op[0] = *(float4*)&res[0];
    op[1] = *(float4*)&res[4];
}

// Stage 2: grid (B_, 2, SLICES). Min over NJC chunks (fully unrolled ->
// batched vmcnt loads), then block-sum -> sums[dir][b][slice].
__global__ __launch_bounds__(THREADS)
void cd_combine_kernel(const float* __restrict__ partial,
                       float* __restrict__ sums) {
    const int b     = blockIdx.x;
    const int dir   = blockIdx.y;
    const int slice = blockIdx.z;
    const int t     = (int)threadIdx.x;
    const int i     = slice * THREADS + t;

    const float* __restrict__ p =
        partial + ((size_t)dir * B_ + b) * (size_t)NJC * N_ + i;

    float m = FLT_MAX;
    #pragma unroll
    for (int c = 0; c < NJC; ++c)
        m = fminf(m, p[(size_t)c * N_]);

    float s = m;
    #pragma unroll
    for (int o = 32; o > 0; o >>= 1)
        s += __shfl_down(s, o, 64);

    __shared__ float red[THREADS / 64];
    if ((t & 63) == 0) red[t >> 6] = s;
    __syncthreads();
    if (t == 0) {
        float tot = 0.0f;
        #pragma unroll
        for (int w = 0; w < THREADS / 64; ++w) tot += red[w];
        sums[((size_t)dir * B_ + b) * SLICES + slice] = tot;
    }
}

// Stage 3: one block. Thread t -> b = t/16, k = t%16 -> (dir, slice).
__global__ __launch_bounds__(THREADS)
void cd_final_kernel(const float* __restrict__ sums,
                     float* __restrict__ out) {
    const int t   = (int)threadIdx.x;
    const int b   = t >> 4;
    const int k   = t & 15;
    const int dir = k >> 3;
    const int sl  = k & 7;

    float v = sums[((size_t)dir * B_ + b) * SLICES + sl];
    v += __shfl_down(v, 8, 16);
    v += __shfl_down(v, 4, 16);
    v += __shfl_down(v, 2, 16);
    v += __shfl_down(v, 1, 16);
    if (k == 0) out[b] = v * (1.0f / (float)N_);
}

extern "C" void kernel_launch(void* const* d_in, const int* in_sizes, int n_in,
                              void* d_out, int out_size, void* d_ws, size_t ws_size,
                              hipStream_t stream) {
    const float* x = (const float*)d_in[0];
    const float* y = (const float*)d_in[1];
    float* out     = (float*)d_out;
    float* partial = (float*)d_ws;   // 2*16*32*2048*4 = 8 MiB + sums

    float* sums = partial + 2ull * B_ * NJC * N_;

    cd_min_kernel<<<dim3(NJC, B_, 2), dim3(THREADS), 0, stream>>>(x, y, partial);
    cd_combine_kernel<<<dim3(B_, 2, SLICES), dim3(THREADS), 0, stream>>>(partial, sums);
    cd_final_kernel<<<dim3(1), dim3(THREADS), 0, stream>>>(sums, out);
}